// Round 9
// baseline (326.196 us; speedup 1.0000x reference)
//
#include <hip/hip_runtime.h>
#include <hip/hip_bf16.h>
#include <stdint.h>

typedef __bf16 bf16;
typedef __bf16 bf16x4 __attribute__((ext_vector_type(4)));
typedef __bf16 bf16x8 __attribute__((ext_vector_type(8)));
typedef float floatx4 __attribute__((ext_vector_type(4)));

#define B_SEQ 16
#define NLBL  5000
#define DLAT  1024
#define PDIM  1100
#define NROWS (B_SEQ * NLBL)   // 80000

// NOTE (R6): never use the builtin's immediate-offset arg — it mis-addresses.
// NOTE (R8): 32x32 MFMA frag reads 4-way bank-conflict under this LDS layout.
// NOTE (R11/R12/R13/R15 ALL FAILED, R14 NULL): K4 schedule is CONVERGED at the
// R10/R14 form (177-183us, ~940TF, MfmaUtil 39.5%). Do NOT perturb K4's
// barrier/stage/read placement again.
// NOTE (R16 partial-null): XCD-pinning K3's writers gained only ~4-9us —
// write-thrash theory mostly falsified. R12's data shows K3 = ~75us GEMM +
// ~36us h1-write: the GEMM is the cost, at 2.5 blocks/CU it runs ~134TF
// (grid-limited occupancy; drain not hidden).
// NOTE (R17): K3 tile 64x128 -> 64x64, grid 632 -> 1264 active (~5 blk/CU).
// m92 reference: 64^2 tile sustains 343TF at scale. XCD pin kept (bid&7=y&7).
__device__ __forceinline__ void gload_lds16(const bf16* g, bf16* l) {
    __builtin_amdgcn_global_load_lds(
        (const __attribute__((address_space(1))) void*)g,
        (__attribute__((address_space(3))) void*)l, 16, 0, 0);
}

__device__ __forceinline__ bf16x8 cvt8(const float* s) {
    floatx4 a = *(const floatx4*)s;
    floatx4 b = *(const floatx4*)(s + 4);
    bf16x8 o;
    o[0] = (bf16)a.x; o[1] = (bf16)a.y; o[2] = (bf16)a.z; o[3] = (bf16)a.w;
    o[4] = (bf16)b.x; o[5] = (bf16)b.y; o[6] = (bf16)b.z; o[7] = (bf16)b.w;
    return o;
}

__device__ __forceinline__ void barx() {
    asm volatile("" ::: "memory");
    __builtin_amdgcn_s_barrier();
    asm volatile("" ::: "memory");
}

// ============ K1: prep ============
#define PSEG_M    256
#define PSEG_LAB  2756
#define PSEG_W2   3268
#define PSEG_PE   3524
#define PSEG_END  3837

__global__ __launch_bounds__(256)
void prep_kernel(const float* __restrict__ label, bf16* __restrict__ label_b,
                 const float* __restrict__ W2, bf16* __restrict__ W2_b,
                 const float* __restrict__ W1, const float* __restrict__ Wl,
                 bf16* __restrict__ M_bf,
                 const float* __restrict__ seq, const float* __restrict__ Wp,
                 float* __restrict__ Pe,
                 float* __restrict__ out, const float* __restrict__ b3) {
    __shared__ bf16 MAs[64 * 72];
    __shared__ bf16 MBs[64 * 72];
    const int blk = blockIdx.x;
    const int t = threadIdx.x;

    if (blk < PSEG_M) {                     // M-product, 64x64 tiles, 16x16 grid
        const int m0 = (blk >> 4) * 64;
        const int n0g = (blk & 15) * 64;
        const int wave = t >> 6, lane = t & 63;
        const int wm = (wave & 1) * 32, wn = (wave >> 1) * 32;
        const int lm = lane & 15, quad = lane >> 4;
        const int a_r = t >> 2, a_c = (t & 3) * 16;
        const int b_kr = t >> 4, b_l = (t & 15) * 4;
        floatx4 acc[2][2] = {};

        for (int k0 = 0; k0 < 1024; k0 += 64) {
            const float* ap = W1 + (size_t)(m0 + a_r) * 2048 + 1024 + k0 + a_c;
            *(bf16x8*)(MAs + a_r * 72 + a_c) = cvt8(ap);
            *(bf16x8*)(MAs + a_r * 72 + a_c + 8) = cvt8(ap + 8);
#pragma unroll
            for (int ps = 0; ps < 4; ++ps) {
                int kr = b_kr + ps * 16;
                floatx4 v = *(const floatx4*)(Wl + (size_t)(k0 + kr) * 1024 + n0g + b_l);
                MBs[(b_l + 0) * 72 + kr] = (bf16)v.x;
                MBs[(b_l + 1) * 72 + kr] = (bf16)v.y;
                MBs[(b_l + 2) * 72 + kr] = (bf16)v.z;
                MBs[(b_l + 3) * 72 + kr] = (bf16)v.w;
            }
            __syncthreads();
#pragma unroll
            for (int ks = 0; ks < 2; ++ks) {
                bf16x8 af[2], bg[2];
#pragma unroll
                for (int mi = 0; mi < 2; ++mi)
                    af[mi] = *(const bf16x8*)(MAs + (wm + mi * 16 + lm) * 72 + ks * 32 + quad * 8);
#pragma unroll
                for (int ni = 0; ni < 2; ++ni)
                    bg[ni] = *(const bf16x8*)(MBs + (wn + ni * 16 + lm) * 72 + ks * 32 + quad * 8);
#pragma unroll
                for (int mi = 0; mi < 2; ++mi)
#pragma unroll
                    for (int ni = 0; ni < 2; ++ni)
                        acc[mi][ni] = __builtin_amdgcn_mfma_f32_16x16x32_bf16(af[mi], bg[ni], acc[mi][ni], 0, 0, 0);
            }
            __syncthreads();
        }
#pragma unroll
        for (int mi = 0; mi < 2; ++mi)
#pragma unroll
            for (int r = 0; r < 4; ++r)
#pragma unroll
                for (int ni = 0; ni < 2; ++ni)
                    M_bf[(size_t)(m0 + wm + mi * 16 + quad * 4 + r) * 1024 + n0g + wn + ni * 16 + lm] =
                        (bf16)acc[mi][ni][r];
    } else if (blk < PSEG_LAB) {            // label convert
        int i = (blk - PSEG_M) * 256 + t;
        ((bf16x8*)label_b)[i] = cvt8(label + (size_t)i * 8);
    } else if (blk < PSEG_W2) {             // W2 convert
        int i = (blk - PSEG_LAB) * 256 + t;
        ((bf16x8*)W2_b)[i] = cvt8(W2 + (size_t)i * 8);
    } else if (blk < PSEG_PE) {             // Pe, wave per d
        int w = (blk - PSEG_W2) * 4 + (t >> 6);
        int l = t & 63;
        floatx4 wv[5];
#pragma unroll
        for (int k = 0; k < 5; ++k) {
            int g = l + 64 * k;
            wv[k] = (g < 275) ? *(const floatx4*)(Wp + (size_t)w * PDIM + g * 4)
                              : floatx4{0.f, 0.f, 0.f, 0.f};
        }
        for (int b = 0; b < B_SEQ; ++b) {
            float acc = 0.f;
#pragma unroll
            for (int k = 0; k < 5; ++k) {
                int g = l + 64 * k;
                if (g < 275) {
                    floatx4 sv = *(const floatx4*)(seq + (size_t)b * PDIM + g * 4);
                    acc += wv[k].x * sv.x + wv[k].y * sv.y + wv[k].z * sv.z + wv[k].w * sv.w;
                }
            }
#pragma unroll
            for (int off = 32; off; off >>= 1) acc += __shfl_xor(acc, off, 64);
            if (l == 0) Pe[b * DLAT + w] = acc;
        }
    } else {                                // out init
        int i = (blk - PSEG_PE) * 256 + t;
        if (i < NROWS) out[i] = b3[0];
    }
}

// ============ K2: hpb[b,o] = b1[o] + Pe[b,:].W1[o,0:1024]  (f32 exact) ============

__global__ __launch_bounds__(256)
void hpb_kernel(const float* __restrict__ Pe, const float* __restrict__ W1,
                const float* __restrict__ b1, float* __restrict__ hpb) {
    int w = blockIdx.x * 4 + (threadIdx.x >> 6);
    int l = threadIdx.x & 63;
    floatx4 wv[4];
#pragma unroll
    for (int k = 0; k < 4; ++k)
        wv[k] = *(const floatx4*)(W1 + (size_t)w * 2048 + (l + 64 * k) * 4);
    for (int b = 0; b < B_SEQ; ++b) {
        float acc = 0.f;
#pragma unroll
        for (int k = 0; k < 4; ++k) {
            floatx4 pv = *(const floatx4*)(Pe + (size_t)b * DLAT + (l + 64 * k) * 4);
            acc += wv[k].x * pv.x + wv[k].y * pv.y + wv[k].z * pv.z + wv[k].w * pv.w;
        }
#pragma unroll
        for (int off = 32; off; off >>= 1) acc += __shfl_xor(acc, off, 64);
        if (l == 0) hpb[b * DLAT + w] = acc + b1[w];
    }
}

// ============ K3: hl GEMM (label @ M.T) with coalesced h1 epilogue ============
// R17: 64x64 tiles, 4 waves (2n x 2d of 32x32), grid 1280 (1264 active,
// ~5 blk/CU). Decode keeps R16's XCD pin: ylo=bid&7, x=(bid>>3)&15,
// yhi=bid>>7, y=ylo+8*yhi, d0=x*64 — all 16 d-chunk writers of one row-set
// share an XCD. h1[(b*5000+n), d] = bf16(relu(hpb[b,d] + hl[n,d])).

__global__ __launch_bounds__(256)
void hl_h1_kernel(const bf16* __restrict__ A, const bf16* __restrict__ Bt,
                  const float* __restrict__ hpb, bf16* __restrict__ h1) {
    __shared__ __align__(16) char smem[16384];
    bf16* As = (bf16*)smem;                 // 64 x 64 = 8 KB (K-loop)
    bf16* Bs = (bf16*)(smem + 8192);        // 64 x 64 = 8 KB (K-loop)
    bf16* Ls = (bf16*)smem;                 // 64*72*2 = 9216 B (epilogue)
    float* hpbs = (float*)(smem + 9216);    // 16*64*4 = 4096 B (epilogue)

    const int bid = blockIdx.x;
    const int ylo = bid & 7;
    const int rr_ = bid >> 3;
    const int x = rr_ & 15;
    const int yhi = rr_ >> 4;               // 0..9
    const int y = ylo + 8 * yhi;            // 0..79
    if (y >= 79) return;                    // uniform early exit (before syncs)

    const int t = threadIdx.x;
    const int d0 = x * 64;                  // d-tile (16)
    const int n0 = y * 64;                  // n-tile (79, last partial)
    const int wave = t >> 6, lane = t & 63;
    const int wm = (wave & 1) * 32;         // n offset within 64
    const int wn = (wave >> 1) * 32;        // d offset within 64
    const int lm = lane & 15, quad = lane >> 4;
    const int sw = lm & 7;

    floatx4 acc[2][2] = {};

    for (int k0 = 0; k0 < 1024; k0 += 64) {
#pragma unroll
        for (int i = 0; i < 2; ++i) {       // A: 64 label rows
            int s = t + i * 256;            // 0..511
            int row = s >> 3;               // 0..63
            int cg = (s & 7) ^ (row & 7);
            int grow = n0 + row; if (grow >= NLBL) grow = NLBL - 1;
            gload_lds16(A + (size_t)grow * 1024 + k0 + cg * 8, As + s * 8);
        }
#pragma unroll
        for (int i = 0; i < 2; ++i) {       // B: 64 M_bf rows (d)
            int s = t + i * 256;
            int row = s >> 3;
            int cg = (s & 7) ^ (row & 7);
            gload_lds16(Bt + (size_t)(d0 + row) * 1024 + k0 + cg * 8, Bs + s * 8);
        }
        __syncthreads();
#pragma unroll
        for (int k = 0; k < 64; k += 32) {
            bf16x8 af[2], bg[2];
            int ko = (((k >> 3) + quad) ^ sw) * 8;
#pragma unroll
            for (int mi = 0; mi < 2; ++mi)
                af[mi] = *(const bf16x8*)(As + (wm + mi * 16 + lm) * 64 + ko);
#pragma unroll
            for (int ni = 0; ni < 2; ++ni)
                bg[ni] = *(const bf16x8*)(Bs + (wn + ni * 16 + lm) * 64 + ko);
#pragma unroll
            for (int mi = 0; mi < 2; ++mi)
#pragma unroll
                for (int ni = 0; ni < 2; ++ni)
                    acc[mi][ni] = __builtin_amdgcn_mfma_f32_16x16x32_bf16(af[mi], bg[ni], acc[mi][ni], 0, 0, 0);
        }
        __syncthreads();
    }

    // acc -> Ls (bf16 hl tile, rows n 0..63, cols d 0..63), stage hpb slice
#pragma unroll
    for (int mi = 0; mi < 2; ++mi)
#pragma unroll
        for (int r = 0; r < 4; ++r)
#pragma unroll
            for (int ni = 0; ni < 2; ++ni)
                Ls[(wm + mi * 16 + quad * 4 + r) * 72 + wn + ni * 16 + lm] =
                    (bf16)acc[mi][ni][r];
    {
        int b = t >> 4;                     // 0..15
        int dl = (t & 15) * 4;              // 0..60
        *(floatx4*)(hpbs + b * 64 + dl) =
            *(const floatx4*)(hpb + (size_t)b * DLAT + d0 + dl);
    }
    __syncthreads();

    // read hl rows once, then 16 b passes of add+relu+bf16x8 stores
    const int g = t & 7;                    // d-granule (16B, 8 per row)
    const int r0 = t >> 3;                  // 0..31 base row
    bf16x8 hlv[2];
#pragma unroll
    for (int p = 0; p < 2; ++p)
        hlv[p] = *(const bf16x8*)(Ls + (p * 32 + r0) * 72 + g * 8);

    for (int b = 0; b < B_SEQ; ++b) {
        floatx4 h0 = *(const floatx4*)(hpbs + b * 64 + g * 8);
        floatx4 h4 = *(const floatx4*)(hpbs + b * 64 + g * 8 + 4);
        size_t rowbase = (size_t)b * NLBL * 1024;
#pragma unroll
        for (int p = 0; p < 2; ++p) {
            int n = n0 + p * 32 + r0;
            if (n >= NLBL) continue;
            bf16x8 o;
            o[0] = (bf16)fmaxf((float)hlv[p][0] + h0.x, 0.f);
            o[1] = (bf16)fmaxf((float)hlv[p][1] + h0.y, 0.f);
            o[2] = (bf16)fmaxf((float)hlv[p][2] + h0.z, 0.f);
            o[3] = (bf16)fmaxf((float)hlv[p][3] + h0.w, 0.f);
            o[4] = (bf16)fmaxf((float)hlv[p][4] + h4.x, 0.f);
            o[5] = (bf16)fmaxf((float)hlv[p][5] + h4.y, 0.f);
            o[6] = (bf16)fmaxf((float)hlv[p][6] + h4.z, 0.f);
            o[7] = (bf16)fmaxf((float)hlv[p][7] + h4.w, 0.f);
            *(bf16x8*)(h1 + rowbase + (size_t)n * 1024 + d0 + g * 8) = o;
        }
    }
}

// ============ K4: main GEMM h1 @ W2.T — R14 schedule (VERIFIED BEST, frozen) ====
// 512 thr = 8 waves (2M x 4N), BK=64, 2-dbuf, stage A in ph1 / B in ph2,
// single vmcnt(0) at end of ph4, ks-outer MFMA. 177-183us / ~940TF.

__device__ __forceinline__ void stage_A256(const bf16* __restrict__ src, bf16* dst,
                                           int m0, int kc, int t) {
#pragma unroll
    for (int i = 0; i < 4; ++i) {
        int s = t + i * 512;                // 0..2047
        int row = s >> 3;                   // 0..255
        int cg = (s & 7) ^ (row & 7);
        int grow = m0 + row;
        if (grow >= NROWS) grow = NROWS - 1;    // last m-tile is half-valid
        gload_lds16(src + (size_t)grow * 1024 + kc + cg * 8, dst + s * 8);
    }
}

__device__ __forceinline__ void stage_B256(const bf16* __restrict__ src, bf16* dst,
                                           int n0, int kc, int t) {
#pragma unroll
    for (int i = 0; i < 4; ++i) {
        int s = t + i * 512;
        int row = s >> 3;
        int cg = (s & 7) ^ (row & 7);
        gload_lds16(src + (size_t)(n0 + row) * 1024 + kc + cg * 8, dst + s * 8);
    }
}

__global__ __launch_bounds__(512, 2)
void gemm_h2(const bf16* __restrict__ h1, const bf16* __restrict__ W2b,
             const float* __restrict__ b2, const float* __restrict__ W3,
             float* __restrict__ out) {
    __shared__ bf16 As[32768];              // 2 x [256][64]
    __shared__ bf16 Bs[32768];              // 2 x [256][64]
    const int t = threadIdx.x;

    // bijective XCD swizzle over nwg=1252 (q=156, r=4; m204 formula)
    int orig = blockIdx.x;
    int xcd = orig & 7, idx = orig >> 3;
    int wg = (xcd < 4 ? xcd * 157 : 628 + (xcd - 4) * 156) + idx;
    const int mt = wg >> 2, nt = wg & 3;    // 313 m-tiles x 4 n-tiles
    const int m0 = mt * 256, n0 = nt * 256;

    const int wave = t >> 6, lane = t & 63;
    const int wr = wave >> 2, wc = wave & 3;
    const int wrow = wr * 128, wcol = wc * 64;
    const int lm = lane & 15, quad = lane >> 4;
    const int swz = lm & 7;

    floatx4 acc[8][4] = {};

    // prologue: stage K-tile 0 into dbuf 0
    stage_A256(h1, As, m0, 0, t);
    stage_B256(W2b, Bs, n0, 0, t);
    asm volatile("s_waitcnt vmcnt(0)" ::: "memory");
    barx();

    for (int kt = 0; kt < 16; ++kt) {
        const int db = kt & 1;
        const bf16* Ad = As + db * 16384;
        const bf16* Bd = Bs + db * 16384;
        bf16* An = As + (db ^ 1) * 16384;
        bf16* Bn = Bs + (db ^ 1) * 16384;
        const bool pf = (kt < 15);
        const int kc = (kt + 1) * 64;

        bf16x8 a[4][2], blo[2][2], bhi[2][2];

        // ---- phase 1: frags A(mh0)+B(nh0) [12 ds_read_b128]; stage next A ----
#pragma unroll
        for (int mi = 0; mi < 4; ++mi) {
            const bf16* rp = Ad + (wrow + mi * 16 + lm) * 64;
            a[mi][0] = *(const bf16x8*)(rp + ((quad ^ swz) << 3));
            a[mi][1] = *(const bf16x8*)(rp + (((4 + quad) ^ swz) << 3));
        }
#pragma unroll
        for (int ni = 0; ni < 2; ++ni) {
            const bf16* rp = Bd + (wcol + ni * 16 + lm) * 64;
            blo[ni][0] = *(const bf16x8*)(rp + ((quad ^ swz) << 3));
            blo[ni][1] = *(const bf16x8*)(rp + (((4 + quad) ^ swz) << 3));
        }
        if (pf) stage_A256(h1, An, m0, kc, t);
        barx();
        __builtin_amdgcn_s_setprio(1);
#pragma unroll
        for (int ks = 0; ks < 2; ++ks)
#pragma unroll
            for (int mi = 0; mi < 4; ++mi)
#pragma unroll
                for (int ni = 0; ni < 2; ++ni)
                    acc[mi][ni] = __builtin_amdgcn_mfma_f32_16x16x32_bf16(a[mi][ks], blo[ni][ks], acc[mi][ni], 0, 0, 0);
        __builtin_amdgcn_s_setprio(0);
        barx();

        // ---- phase 2: frags B(nh1) [4 ds_read_b128]; stage next B ----
#pragma unroll
        for (int ni = 0; ni < 2; ++ni) {
            const bf16* rp = Bd + (wcol + 32 + ni * 16 + lm) * 64;
            bhi[ni][0] = *(const bf16x8*)(rp + ((quad ^ swz) << 3));
            bhi[ni][1] = *(const bf16x8*)(rp + (((4 + quad) ^ swz) << 3));
        }
        if (pf) stage_B256(W2b, Bn, n0, kc, t);
        barx();
        __builtin_amdgcn_s_setprio(1);
#pragma unroll
        for (int ks = 0; ks < 2; ++ks)
#pragma unroll
            for (int mi = 0; mi < 4; ++mi)
#pragma unroll
                for (int ni = 0; ni < 2; ++ni)
                    acc[mi][2 + ni] = __builtin_amdgcn_mfma_f32_16x16x32_bf16(a[mi][ks], bhi[ni][ks], acc[mi][2 + ni], 0, 0, 0);
        __builtin_amdgcn_s_setprio(0);
        barx();

        // ---- phase 3: frags A(mh1) [8 ds_read_b128] ----
#pragma unroll
        for (int mi = 0; mi < 4; ++mi) {
            const bf16* rp = Ad + (wrow + 64 + mi * 16 + lm) * 64;
            a[mi][0] = *(const bf16x8*)(rp + ((quad ^ swz) << 3));
            a[mi][1] = *(const bf16x8*)(rp + (((4 + quad) ^ swz) << 3));
        }
        barx();
        __builtin_amdgcn_s_setprio(1);
#pragma unroll
        for (int ks = 0; ks < 2; ++ks)
#pragma unroll
            for (int mi = 0; mi < 4; ++mi)
#pragma unroll
                for (int ni = 0; ni < 2; ++ni)
                    acc[4 + mi][2 + ni] = __builtin_amdgcn_mfma_f32_16x16x32_bf16(a[mi][ks], bhi[ni][ks], acc[4 + mi][2 + ni], 0, 0, 0);
        __builtin_amdgcn_s_setprio(0);
        barx();

        // ---- phase 4: pure-reg MFMA; drain staging loads; buffer swap ----
        __builtin_amdgcn_s_setprio(1);
#pragma unroll
        for (int ks = 0; ks < 2; ++ks)
#pragma unroll
            for (int mi = 0; mi < 4; ++mi)
#pragma unroll
                for (int ni = 0; ni < 2; ++ni)
                    acc[4 + mi][ni] = __builtin_amdgcn_mfma_f32_16x16x32_bf16(a[mi][ks], blo[ni][ks], acc[4 + mi][ni], 0, 0, 0);
        __builtin_amdgcn_s_setprio(0);
        asm volatile("s_waitcnt vmcnt(0)" ::: "memory");
        barx();
    }

    // fused epilogue: out[row] += sum_col relu(acc + b2) * W3
    float w3v[4], b2v[4];
#pragma unroll
    for (int ni = 0; ni < 4; ++ni) {
        int col = n0 + wcol + ni * 16 + lm;
        w3v[ni] = W3[col];
        b2v[ni] = b2[col];
    }
#pragma unroll
    for (int mi = 0; mi < 8; ++mi) {
#pragma unroll
        for (int r = 0; r < 4; ++r) {
            float sacc = 0.f;
#pragma unroll
            for (int ni = 0; ni < 4; ++ni)
                sacc += fmaxf(acc[mi][ni][r] + b2v[ni], 0.f) * w3v[ni];
            sacc += __shfl_xor(sacc, 1, 64);
            sacc += __shfl_xor(sacc, 2, 64);
            sacc += __shfl_xor(sacc, 4, 64);
            sacc += __shfl_xor(sacc, 8, 64);
            int row = m0 + wrow + mi * 16 + quad * 4 + r;
            if (lm == 0 && row < NROWS)
                atomicAdd(out + row, sacc);
        }
    }
}

// ---------------- launch ----------------

extern "C" void kernel_launch(void* const* d_in, const int* in_sizes, int n_in,
                              void* d_out, int out_size, void* d_ws, size_t ws_size,
                              hipStream_t stream) {
    const float* seq   = (const float*)d_in[0];
    const float* label = (const float*)d_in[1];
    const float* Wp    = (const float*)d_in[2];
    const float* Wl    = (const float*)d_in[3];
    const float* W1    = (const float*)d_in[4];
    const float* b1    = (const float*)d_in[5];
    const float* W2    = (const float*)d_in[6];
    const float* b2    = (const float*)d_in[7];
    const float* W3    = (const float*)d_in[8];
    const float* b3    = (const float*)d_in[9];
    float* out = (float*)d_out;
    (void)n_in; (void)in_sizes; (void)out_size; (void)ws_size;

    size_t off = 0;
    auto alloc = [&](size_t bytes) {
        void* p = (char*)d_ws + off;
        off += (bytes + 255) & ~(size_t)255;
        return p;
    };
    bf16* label_b = (bf16*)alloc((size_t)NLBL * 1024 * 2);
    bf16* W2_b    = (bf16*)alloc((size_t)1024 * 1024 * 2);
    bf16* M_bf    = (bf16*)alloc((size_t)1024 * 1024 * 2);
    float* Pe     = (float*)alloc((size_t)B_SEQ * 1024 * 4);
    float* hpb    = (float*)alloc((size_t)B_SEQ * 1024 * 4);
    bf16* h1      = (bf16*)alloc((size_t)NROWS * 1024 * 2);

    prep_kernel<<<PSEG_END, 256, 0, stream>>>(label, label_b, W2, W2_b, W1, Wl,
                                              M_bf, seq, Wp, Pe, out, b3);
    hpb_kernel<<<256, 256, 0, stream>>>(Pe, W1, b1, hpb);
    hl_h1_kernel<<<1280, 256, 0, stream>>>(label_b, M_bf, hpb, h1);
    gemm_h2<<<1252, 512, 0, stream>>>(h1, W2_b, b2, W3, out);
}

// Round 10
// 325.327 us; speedup vs baseline: 1.0027x; 1.0027x over previous
//
#include <hip/hip_runtime.h>
#include <hip/hip_bf16.h>
#include <stdint.h>

typedef __bf16 bf16;
typedef __bf16 bf16x4 __attribute__((ext_vector_type(4)));
typedef __bf16 bf16x8 __attribute__((ext_vector_type(8)));
typedef float floatx4 __attribute__((ext_vector_type(4)));

#define B_SEQ 16
#define NLBL  5000
#define DLAT  1024
#define PDIM  1100
#define NROWS (B_SEQ * NLBL)   // 80000

// NOTE (R6): never use the builtin's immediate-offset arg — it mis-addresses.
// NOTE (R8): 32x32 MFMA frag reads 4-way bank-conflict under this LDS layout.
// NOTE (R11/R12/R13/R15 ALL FAILED, R14 NULL): K4 schedule is CONVERGED at the
// R10/R14 form (177-183us, ~940TF). Do NOT perturb K4 again.
// NOTE (R16 partial-null): XCD-pinning K3's writers gained ~4us. Keep (free).
// NOTE (R17 NULL): 64x64 tile @2x grid = 326us — halving per-block FLOP
// doubled total fixed overhead (16 drain+barrier events/block) and raised
// bytes/FLOP 33%. Reverted to 64x128.
// NOTE (R18): K3's real defect = ZERO stage/compute overlap (stage->sync->
// compute->sync). Port K4's verified R10 discipline: dbuf, stage next tile
// BEFORE current MFMA, single vmcnt(0)+barrier per K-step (half the
// barriers, drain under compute).
__device__ __forceinline__ void gload_lds16(const bf16* g, bf16* l) {
    __builtin_amdgcn_global_load_lds(
        (const __attribute__((address_space(1))) void*)g,
        (__attribute__((address_space(3))) void*)l, 16, 0, 0);
}

__device__ __forceinline__ bf16x8 cvt8(const float* s) {
    floatx4 a = *(const floatx4*)s;
    floatx4 b = *(const floatx4*)(s + 4);
    bf16x8 o;
    o[0] = (bf16)a.x; o[1] = (bf16)a.y; o[2] = (bf16)a.z; o[3] = (bf16)a.w;
    o[4] = (bf16)b.x; o[5] = (bf16)b.y; o[6] = (bf16)b.z; o[7] = (bf16)b.w;
    return o;
}

__device__ __forceinline__ void barx() {
    asm volatile("" ::: "memory");
    __builtin_amdgcn_s_barrier();
    asm volatile("" ::: "memory");
}

// ============ K1: prep ============
#define PSEG_M    256
#define PSEG_LAB  2756
#define PSEG_W2   3268
#define PSEG_PE   3524
#define PSEG_END  3837

__global__ __launch_bounds__(256)
void prep_kernel(const float* __restrict__ label, bf16* __restrict__ label_b,
                 const float* __restrict__ W2, bf16* __restrict__ W2_b,
                 const float* __restrict__ W1, const float* __restrict__ Wl,
                 bf16* __restrict__ M_bf,
                 const float* __restrict__ seq, const float* __restrict__ Wp,
                 float* __restrict__ Pe,
                 float* __restrict__ out, const float* __restrict__ b3) {
    __shared__ bf16 MAs[64 * 72];
    __shared__ bf16 MBs[64 * 72];
    const int blk = blockIdx.x;
    const int t = threadIdx.x;

    if (blk < PSEG_M) {                     // M-product, 64x64 tiles, 16x16 grid
        const int m0 = (blk >> 4) * 64;
        const int n0g = (blk & 15) * 64;
        const int wave = t >> 6, lane = t & 63;
        const int wm = (wave & 1) * 32, wn = (wave >> 1) * 32;
        const int lm = lane & 15, quad = lane >> 4;
        const int a_r = t >> 2, a_c = (t & 3) * 16;
        const int b_kr = t >> 4, b_l = (t & 15) * 4;
        floatx4 acc[2][2] = {};

        for (int k0 = 0; k0 < 1024; k0 += 64) {
            const float* ap = W1 + (size_t)(m0 + a_r) * 2048 + 1024 + k0 + a_c;
            *(bf16x8*)(MAs + a_r * 72 + a_c) = cvt8(ap);
            *(bf16x8*)(MAs + a_r * 72 + a_c + 8) = cvt8(ap + 8);
#pragma unroll
            for (int ps = 0; ps < 4; ++ps) {
                int kr = b_kr + ps * 16;
                floatx4 v = *(const floatx4*)(Wl + (size_t)(k0 + kr) * 1024 + n0g + b_l);
                MBs[(b_l + 0) * 72 + kr] = (bf16)v.x;
                MBs[(b_l + 1) * 72 + kr] = (bf16)v.y;
                MBs[(b_l + 2) * 72 + kr] = (bf16)v.z;
                MBs[(b_l + 3) * 72 + kr] = (bf16)v.w;
            }
            __syncthreads();
#pragma unroll
            for (int ks = 0; ks < 2; ++ks) {
                bf16x8 af[2], bg[2];
#pragma unroll
                for (int mi = 0; mi < 2; ++mi)
                    af[mi] = *(const bf16x8*)(MAs + (wm + mi * 16 + lm) * 72 + ks * 32 + quad * 8);
#pragma unroll
                for (int ni = 0; ni < 2; ++ni)
                    bg[ni] = *(const bf16x8*)(MBs + (wn + ni * 16 + lm) * 72 + ks * 32 + quad * 8);
#pragma unroll
                for (int mi = 0; mi < 2; ++mi)
#pragma unroll
                    for (int ni = 0; ni < 2; ++ni)
                        acc[mi][ni] = __builtin_amdgcn_mfma_f32_16x16x32_bf16(af[mi], bg[ni], acc[mi][ni], 0, 0, 0);
            }
            __syncthreads();
        }
#pragma unroll
        for (int mi = 0; mi < 2; ++mi)
#pragma unroll
            for (int r = 0; r < 4; ++r)
#pragma unroll
                for (int ni = 0; ni < 2; ++ni)
                    M_bf[(size_t)(m0 + wm + mi * 16 + quad * 4 + r) * 1024 + n0g + wn + ni * 16 + lm] =
                        (bf16)acc[mi][ni][r];
    } else if (blk < PSEG_LAB) {            // label convert
        int i = (blk - PSEG_M) * 256 + t;
        ((bf16x8*)label_b)[i] = cvt8(label + (size_t)i * 8);
    } else if (blk < PSEG_W2) {             // W2 convert
        int i = (blk - PSEG_LAB) * 256 + t;
        ((bf16x8*)W2_b)[i] = cvt8(W2 + (size_t)i * 8);
    } else if (blk < PSEG_PE) {             // Pe, wave per d
        int w = (blk - PSEG_W2) * 4 + (t >> 6);
        int l = t & 63;
        floatx4 wv[5];
#pragma unroll
        for (int k = 0; k < 5; ++k) {
            int g = l + 64 * k;
            wv[k] = (g < 275) ? *(const floatx4*)(Wp + (size_t)w * PDIM + g * 4)
                              : floatx4{0.f, 0.f, 0.f, 0.f};
        }
        for (int b = 0; b < B_SEQ; ++b) {
            float acc = 0.f;
#pragma unroll
            for (int k = 0; k < 5; ++k) {
                int g = l + 64 * k;
                if (g < 275) {
                    floatx4 sv = *(const floatx4*)(seq + (size_t)b * PDIM + g * 4);
                    acc += wv[k].x * sv.x + wv[k].y * sv.y + wv[k].z * sv.z + wv[k].w * sv.w;
                }
            }
#pragma unroll
            for (int off = 32; off; off >>= 1) acc += __shfl_xor(acc, off, 64);
            if (l == 0) Pe[b * DLAT + w] = acc;
        }
    } else {                                // out init
        int i = (blk - PSEG_PE) * 256 + t;
        if (i < NROWS) out[i] = b3[0];
    }
}

// ============ K2: hpb[b,o] = b1[o] + Pe[b,:].W1[o,0:1024]  (f32 exact) ============

__global__ __launch_bounds__(256)
void hpb_kernel(const float* __restrict__ Pe, const float* __restrict__ W1,
                const float* __restrict__ b1, float* __restrict__ hpb) {
    int w = blockIdx.x * 4 + (threadIdx.x >> 6);
    int l = threadIdx.x & 63;
    floatx4 wv[4];
#pragma unroll
    for (int k = 0; k < 4; ++k)
        wv[k] = *(const floatx4*)(W1 + (size_t)w * 2048 + (l + 64 * k) * 4);
    for (int b = 0; b < B_SEQ; ++b) {
        float acc = 0.f;
#pragma unroll
        for (int k = 0; k < 4; ++k) {
            floatx4 pv = *(const floatx4*)(Pe + (size_t)b * DLAT + (l + 64 * k) * 4);
            acc += wv[k].x * pv.x + wv[k].y * pv.y + wv[k].z * pv.z + wv[k].w * pv.w;
        }
#pragma unroll
        for (int off = 32; off; off >>= 1) acc += __shfl_xor(acc, off, 64);
        if (l == 0) hpb[b * DLAT + w] = acc + b1[w];
    }
}

// ============ K3: hl GEMM (label @ M.T) + h1 epilogue — R18 dbuf pipeline ====
// 64x128 tile, grid 640 (632 active), R16 XCD-pin decode. Double-buffered
// LDS (2 x 24KB); per K-step: stage next tile FIRST, then frags+MFMA on
// current, then single vmcnt(0)+barrier. Half the barriers, drain covered.

__global__ __launch_bounds__(256)
void hl_h1_kernel(const bf16* __restrict__ A, const bf16* __restrict__ Bt,
                  const float* __restrict__ hpb, bf16* __restrict__ h1) {
    __shared__ __align__(16) char smem[49152];  // 2 x (As 8KB + Bs 16KB)
    bf16* Ls = (bf16*)smem;                 // 64*136*2 = 17408 B (epilogue)
    float* hpbs = (float*)(smem + 17408);   // 16*128*4 = 8192 B (epilogue)

    const int bid = blockIdx.x;
    const int ylo = bid & 7;
    const int x = (bid >> 3) & 7;
    const int yhi = bid >> 6;
    const int y = ylo + 8 * yhi;            // n-tile 0..79
    if (y >= 79) return;                    // uniform early exit (before syncs)

    const int t = threadIdx.x;
    const int d0 = x * 128;                 // d-tile (8)
    const int n0 = y * 64;                  // n-tile
    const int wave = t >> 6, lane = t & 63;
    const int wm = (wave & 1) * 32;         // n offset within 64
    const int wn = (wave >> 1) * 64;        // d offset within 128
    const int lm = lane & 15, quad = lane >> 4;
    const int sw = lm & 7;
    const int srow = t >> 3;                // 0..31
    const int scg0 = t & 7;
    const int sbase = (t & 192) * 8;

    // stage one K-tile (A 64 rows + B 128 rows) into buffer base
    auto STAGE = [&](int k0, char* base) {
        bf16* As_ = (bf16*)base;
        bf16* Bs_ = (bf16*)(base + 8192);
#pragma unroll
        for (int p = 0; p < 2; ++p) {
            int row = p * 32 + srow;
            int cg = scg0 ^ (row & 7);
            int grow = n0 + row; if (grow >= NLBL) grow = NLBL - 1;
            gload_lds16(A + (size_t)grow * 1024 + k0 + cg * 8, As_ + p * 2048 + sbase);
        }
#pragma unroll
        for (int p = 0; p < 4; ++p) {
            int row = p * 32 + srow;
            int cg = scg0 ^ (row & 7);
            gload_lds16(Bt + (size_t)(d0 + row) * 1024 + k0 + cg * 8, Bs_ + p * 2048 + sbase);
        }
    };

    floatx4 acc[2][4] = {};

    // prologue: tile 0 into buf0
    STAGE(0, smem);
    asm volatile("s_waitcnt vmcnt(0)" ::: "memory");
    barx();

    for (int kt = 0; kt < 16; ++kt) {
        char* cur = smem + (kt & 1) * 24576;
        char* nxt = smem + ((kt + 1) & 1) * 24576;
        const bool pf = (kt < 15);
        if (pf) STAGE((kt + 1) * 64, nxt);  // issue BEFORE compute (R10 rule)

        const bf16* As_ = (const bf16*)cur;
        const bf16* Bs_ = (const bf16*)(cur + 8192);
#pragma unroll
        for (int k = 0; k < 64; k += 32) {
            bf16x8 af[2], bg[4];
            int ko = (((k >> 3) + quad) ^ sw) * 8;
#pragma unroll
            for (int mi = 0; mi < 2; ++mi)
                af[mi] = *(const bf16x8*)(As_ + (wm + mi * 16 + lm) * 64 + ko);
#pragma unroll
            for (int ni = 0; ni < 4; ++ni)
                bg[ni] = *(const bf16x8*)(Bs_ + (wn + ni * 16 + lm) * 64 + ko);
#pragma unroll
            for (int mi = 0; mi < 2; ++mi)
#pragma unroll
                for (int ni = 0; ni < 4; ++ni)
                    acc[mi][ni] = __builtin_amdgcn_mfma_f32_16x16x32_bf16(af[mi], bg[ni], acc[mi][ni], 0, 0, 0);
        }
        if (pf) {
            asm volatile("s_waitcnt vmcnt(0)" ::: "memory");  // next tile landed
            barx();  // all waves done reading cur (reads retired pre-MFMA)
        }
    }

    // epilogue: acc -> Ls (buf0 region; last read of buf0 was kt=14, fenced
    // by its end barrier; kt=15 reads buf1 only — disjoint)
#pragma unroll
    for (int mi = 0; mi < 2; ++mi)
#pragma unroll
        for (int r = 0; r < 4; ++r)
#pragma unroll
            for (int ni = 0; ni < 4; ++ni)
                Ls[(wm + mi * 16 + quad * 4 + r) * 136 + wn + ni * 16 + lm] =
                    (bf16)acc[mi][ni][r];
    {
        int dl = (t & 31) * 4;
        int b = t >> 5;                     // 0..7
        *(floatx4*)(hpbs + b * 128 + dl) =
            *(const floatx4*)(hpb + (size_t)b * DLAT + d0 + dl);
        *(floatx4*)(hpbs + (b + 8) * 128 + dl) =
            *(const floatx4*)(hpb + (size_t)(b + 8) * DLAT + d0 + dl);
    }
    __syncthreads();

    const int g = t & 15;                   // d-granule (16B)
    const int r0 = t >> 4;                  // 0..15 base row
    bf16x8 hlv[4];
#pragma unroll
    for (int p = 0; p < 4; ++p)
        hlv[p] = *(const bf16x8*)(Ls + (p * 16 + r0) * 136 + g * 8);

    for (int b = 0; b < B_SEQ; ++b) {
        floatx4 h0 = *(const floatx4*)(hpbs + b * 128 + g * 8);
        floatx4 h4 = *(const floatx4*)(hpbs + b * 128 + g * 8 + 4);
        size_t rowbase = (size_t)b * NLBL * 1024;
#pragma unroll
        for (int p = 0; p < 4; ++p) {
            int n = n0 + p * 16 + r0;
            if (n >= NLBL) continue;
            bf16x8 o;
            o[0] = (bf16)fmaxf((float)hlv[p][0] + h0.x, 0.f);
            o[1] = (bf16)fmaxf((float)hlv[p][1] + h0.y, 0.f);
            o[2] = (bf16)fmaxf((float)hlv[p][2] + h0.z, 0.f);
            o[3] = (bf16)fmaxf((float)hlv[p][3] + h0.w, 0.f);
            o[4] = (bf16)fmaxf((float)hlv[p][4] + h4.x, 0.f);
            o[5] = (bf16)fmaxf((float)hlv[p][5] + h4.y, 0.f);
            o[6] = (bf16)fmaxf((float)hlv[p][6] + h4.z, 0.f);
            o[7] = (bf16)fmaxf((float)hlv[p][7] + h4.w, 0.f);
            *(bf16x8*)(h1 + rowbase + (size_t)n * 1024 + d0 + g * 8) = o;
        }
    }
}

// ============ K4: main GEMM h1 @ W2.T — R14 schedule (VERIFIED BEST, frozen) ====
// 512 thr = 8 waves (2M x 4N), BK=64, 2-dbuf, stage A in ph1 / B in ph2,
// single vmcnt(0) at end of ph4, ks-outer MFMA. 177-183us / ~940TF.

__device__ __forceinline__ void stage_A256(const bf16* __restrict__ src, bf16* dst,
                                           int m0, int kc, int t) {
#pragma unroll
    for (int i = 0; i < 4; ++i) {
        int s = t + i * 512;                // 0..2047
        int row = s >> 3;                   // 0..255
        int cg = (s & 7) ^ (row & 7);
        int grow = m0 + row;
        if (grow >= NROWS) grow = NROWS - 1;    // last m-tile is half-valid
        gload_lds16(src + (size_t)grow * 1024 + kc + cg * 8, dst + s * 8);
    }
}

__device__ __forceinline__ void stage_B256(const bf16* __restrict__ src, bf16* dst,
                                           int n0, int kc, int t) {
#pragma unroll
    for (int i = 0; i < 4; ++i) {
        int s = t + i * 512;
        int row = s >> 3;
        int cg = (s & 7) ^ (row & 7);
        gload_lds16(src + (size_t)(n0 + row) * 1024 + kc + cg * 8, dst + s * 8);
    }
}

__global__ __launch_bounds__(512, 2)
void gemm_h2(const bf16* __restrict__ h1, const bf16* __restrict__ W2b,
             const float* __restrict__ b2, const float* __restrict__ W3,
             float* __restrict__ out) {
    __shared__ bf16 As[32768];              // 2 x [256][64]
    __shared__ bf16 Bs[32768];              // 2 x [256][64]
    const int t = threadIdx.x;

    // bijective XCD swizzle over nwg=1252 (q=156, r=4; m204 formula)
    int orig = blockIdx.x;
    int xcd = orig & 7, idx = orig >> 3;
    int wg = (xcd < 4 ? xcd * 157 : 628 + (xcd - 4) * 156) + idx;
    const int mt = wg >> 2, nt = wg & 3;    // 313 m-tiles x 4 n-tiles
    const int m0 = mt * 256, n0 = nt * 256;

    const int wave = t >> 6, lane = t & 63;
    const int wr = wave >> 2, wc = wave & 3;
    const int wrow = wr * 128, wcol = wc * 64;
    const int lm = lane & 15, quad = lane >> 4;
    const int swz = lm & 7;

    floatx4 acc[8][4] = {};

    // prologue: stage K-tile 0 into dbuf 0
    stage_A256(h1, As, m0, 0, t);
    stage_B256(W2b, Bs, n0, 0, t);
    asm volatile("s_waitcnt vmcnt(0)" ::: "memory");
    barx();

    for (int kt = 0; kt < 16; ++kt) {
        const int db = kt & 1;
        const bf16* Ad = As + db * 16384;
        const bf16* Bd = Bs + db * 16384;
        bf16* An = As + (db ^ 1) * 16384;
        bf16* Bn = Bs + (db ^ 1) * 16384;
        const bool pf = (kt < 15);
        const int kc = (kt + 1) * 64;

        bf16x8 a[4][2], blo[2][2], bhi[2][2];

        // ---- phase 1: frags A(mh0)+B(nh0) [12 ds_read_b128]; stage next A ----
#pragma unroll
        for (int mi = 0; mi < 4; ++mi) {
            const bf16* rp = Ad + (wrow + mi * 16 + lm) * 64;
            a[mi][0] = *(const bf16x8*)(rp + ((quad ^ swz) << 3));
            a[mi][1] = *(const bf16x8*)(rp + (((4 + quad) ^ swz) << 3));
        }
#pragma unroll
        for (int ni = 0; ni < 2; ++ni) {
            const bf16* rp = Bd + (wcol + ni * 16 + lm) * 64;
            blo[ni][0] = *(const bf16x8*)(rp + ((quad ^ swz) << 3));
            blo[ni][1] = *(const bf16x8*)(rp + (((4 + quad) ^ swz) << 3));
        }
        if (pf) stage_A256(h1, An, m0, kc, t);
        barx();
        __builtin_amdgcn_s_setprio(1);
#pragma unroll
        for (int ks = 0; ks < 2; ++ks)
#pragma unroll
            for (int mi = 0; mi < 4; ++mi)
#pragma unroll
                for (int ni = 0; ni < 2; ++ni)
                    acc[mi][ni] = __builtin_amdgcn_mfma_f32_16x16x32_bf16(a[mi][ks], blo[ni][ks], acc[mi][ni], 0, 0, 0);
        __builtin_amdgcn_s_setprio(0);
        barx();

        // ---- phase 2: frags B(nh1) [4 ds_read_b128]; stage next B ----
#pragma unroll
        for (int ni = 0; ni < 2; ++ni) {
            const bf16* rp = Bd + (wcol + 32 + ni * 16 + lm) * 64;
            bhi[ni][0] = *(const bf16x8*)(rp + ((quad ^ swz) << 3));
            bhi[ni][1] = *(const bf16x8*)(rp + (((4 + quad) ^ swz) << 3));
        }
        if (pf) stage_B256(W2b, Bn, n0, kc, t);
        barx();
        __builtin_amdgcn_s_setprio(1);
#pragma unroll
        for (int ks = 0; ks < 2; ++ks)
#pragma unroll
            for (int mi = 0; mi < 4; ++mi)
#pragma unroll
                for (int ni = 0; ni < 2; ++ni)
                    acc[mi][2 + ni] = __builtin_amdgcn_mfma_f32_16x16x32_bf16(a[mi][ks], bhi[ni][ks], acc[mi][2 + ni], 0, 0, 0);
        __builtin_amdgcn_s_setprio(0);
        barx();

        // ---- phase 3: frags A(mh1) [8 ds_read_b128] ----
#pragma unroll
        for (int mi = 0; mi < 4; ++mi) {
            const bf16* rp = Ad + (wrow + 64 + mi * 16 + lm) * 64;
            a[mi][0] = *(const bf16x8*)(rp + ((quad ^ swz) << 3));
            a[mi][1] = *(const bf16x8*)(rp + (((4 + quad) ^ swz) << 3));
        }
        barx();
        __builtin_amdgcn_s_setprio(1);
#pragma unroll
        for (int ks = 0; ks < 2; ++ks)
#pragma unroll
            for (int mi = 0; mi < 4; ++mi)
#pragma unroll
                for (int ni = 0; ni < 2; ++ni)
                    acc[4 + mi][2 + ni] = __builtin_amdgcn_mfma_f32_16x16x32_bf16(a[mi][ks], bhi[ni][ks], acc[4 + mi][2 + ni], 0, 0, 0);
        __builtin_amdgcn_s_setprio(0);
        barx();

        // ---- phase 4: pure-reg MFMA; drain staging loads; buffer swap ----
        __builtin_amdgcn_s_setprio(1);
#pragma unroll
        for (int ks = 0; ks < 2; ++ks)
#pragma unroll
            for (int mi = 0; mi < 4; ++mi)
#pragma unroll
                for (int ni = 0; ni < 2; ++ni)
                    acc[4 + mi][ni] = __builtin_amdgcn_mfma_f32_16x16x32_bf16(a[mi][ks], blo[ni][ks], acc[4 + mi][ni], 0, 0, 0);
        __builtin_amdgcn_s_setprio(0);
        asm volatile("s_waitcnt vmcnt(0)" ::: "memory");
        barx();
    }

    // fused epilogue: out[row] += sum_col relu(acc + b2) * W3
    float w3v[4], b2v[4];
#pragma unroll
    for (int ni = 0; ni < 4; ++ni) {
        int col = n0 + wcol + ni * 16 + lm;
        w3v[ni] = W3[col];
        b2v[ni] = b2[col];
    }
#pragma unroll
    for (int mi = 0; mi < 8; ++mi) {
#pragma unroll
        for (int r = 0; r < 4; ++r) {
            float sacc = 0.f;
#pragma unroll
            for (int ni = 0; ni < 4; ++ni)
                sacc += fmaxf(acc[mi][ni][r] + b2v[ni], 0.f) * w3v[ni];
            sacc += __shfl_xor(sacc, 1, 64);
            sacc += __shfl_xor(sacc, 2, 64);
            sacc += __shfl_xor(sacc, 4, 64);
            sacc += __shfl_xor(sacc, 8, 64);
            int row = m0 + wrow + mi * 16 + quad * 4 + r;
            if (lm == 0 && row < NROWS)
                atomicAdd(out + row, sacc);
        }
    }
}

// ---------------- launch ----------------

extern "C" void kernel_launch(void* const* d_in, const int* in_sizes, int n_in,
                              void* d_out, int out_size, void* d_ws, size_t ws_size,
                              hipStream_t stream) {
    const float* seq   = (const float*)d_in[0];
    const float* label = (const float*)d_in[1];
    const float* Wp    = (const float*)d_in[2];
    const float* Wl    = (const float*)d_in[3];
    const float* W1    = (const float*)d_in[4];
    const float* b1    = (const float*)d_in[5];
    const float* W2    = (const float*)d_in[6];
    const float* b2    = (const float*)d_in[7];
    const float* W3    = (const float*)d_in[8];
    const float* b3    = (const float*)d_in[9];
    float* out = (float*)d_out;
    (void)n_in; (void)in_sizes; (void)out_size; (void)ws_size;

    size_t off = 0;
    auto alloc = [&](size_t bytes) {
        void* p = (char*)d_ws + off;
        off += (bytes + 255) & ~(size_t)255;
        return p;
    };
    bf16* label_b = (bf16*)alloc((size_t)NLBL * 1024 * 2);
    bf16* W2_b    = (bf16*)alloc((size_t)1024 * 1024 * 2);
    bf16* M_bf    = (bf16*)alloc((size_t)1024 * 1024 * 2);
    float* Pe     = (float*)alloc((size_t)B_SEQ * 1024 * 4);
    float* hpb    = (float*)alloc((size_t)B_SEQ * 1024 * 4);
    bf16* h1      = (bf16*)alloc((size_t)NROWS * 1024 * 2);

    prep_kernel<<<PSEG_END, 256, 0, stream>>>(label, label_b, W2, W2_b, W1, Wl,
                                              M_bf, seq, Wp, Pe, out, b3);
    hpb_kernel<<<256, 256, 0, stream>>>(Pe, W1, b1, hpb);
    hl_h1_kernel<<<640, 256, 0, stream>>>(label_b, M_bf, hpb, h1);
    gemm_h2<<<1252, 512, 0, stream>>>(h1, W2_b, b2, W3, out);
}

// Round 11
// 323.716 us; speedup vs baseline: 1.0077x; 1.0050x over previous
//
#include <hip/hip_runtime.h>
#include <hip/hip_bf16.h>
#include <stdint.h>

typedef __bf16 bf16;
typedef __bf16 bf16x4 __attribute__((ext_vector_type(4)));
typedef __bf16 bf16x8 __attribute__((ext_vector_type(8)));
typedef float floatx4 __attribute__((ext_vector_type(4)));

#define B_SEQ 16
#define NLBL  5000
#define DLAT  1024
#define PDIM  1100
#define NROWS (B_SEQ * NLBL)   // 80000

// NOTE (R6): never use the builtin's immediate-offset arg — it mis-addresses.
// NOTE (R8): 32x32 MFMA frag reads 4-way bank-conflict under this LDS layout.
// NOTE (R11/R12/R13/R15 ALL FAILED, R14 NULL): K4 schedule is CONVERGED at the
// R10/R14 form (177-191us band, ~940TF). Do NOT perturb K4's schedule again.
// NOTE (R16/R17/R18 ~NULL): K3 is INSENSITIVE to loop structure (XCD-pin +4us,
// 2x-grid -3us, dbuf+half-barriers ~0). K3 is memory-path-bound.
// NOTE (R19): h1 row-major made K3 write 256B-per-2KB-row fragments (16
// interleaved b-streams 10MB apart) and K4 read 128B-per-2KB-stride — DRAM
// page fragmentation on both sides. New layout: h1 K-BLOCKED
// h1[kt][b*5000+n][64] (16 slabs x 10MB): K3 writes 8KB-contiguous per
// (b,kt); K4 A-stage reads 32KB-contiguous per K-tile. Address-only change.
__device__ __forceinline__ void gload_lds16(const bf16* g, bf16* l) {
    __builtin_amdgcn_global_load_lds(
        (const __attribute__((address_space(1))) void*)g,
        (__attribute__((address_space(3))) void*)l, 16, 0, 0);
}

__device__ __forceinline__ bf16x8 cvt8(const float* s) {
    floatx4 a = *(const floatx4*)s;
    floatx4 b = *(const floatx4*)(s + 4);
    bf16x8 o;
    o[0] = (bf16)a.x; o[1] = (bf16)a.y; o[2] = (bf16)a.z; o[3] = (bf16)a.w;
    o[4] = (bf16)b.x; o[5] = (bf16)b.y; o[6] = (bf16)b.z; o[7] = (bf16)b.w;
    return o;
}

__device__ __forceinline__ void barx() {
    asm volatile("" ::: "memory");
    __builtin_amdgcn_s_barrier();
    asm volatile("" ::: "memory");
}

// ============ K1: prep ============
#define PSEG_M    256
#define PSEG_LAB  2756
#define PSEG_W2   3268
#define PSEG_PE   3524
#define PSEG_END  3837

__global__ __launch_bounds__(256)
void prep_kernel(const float* __restrict__ label, bf16* __restrict__ label_b,
                 const float* __restrict__ W2, bf16* __restrict__ W2_b,
                 const float* __restrict__ W1, const float* __restrict__ Wl,
                 bf16* __restrict__ M_bf,
                 const float* __restrict__ seq, const float* __restrict__ Wp,
                 float* __restrict__ Pe,
                 float* __restrict__ out, const float* __restrict__ b3) {
    __shared__ bf16 MAs[64 * 72];
    __shared__ bf16 MBs[64 * 72];
    const int blk = blockIdx.x;
    const int t = threadIdx.x;

    if (blk < PSEG_M) {                     // M-product, 64x64 tiles, 16x16 grid
        const int m0 = (blk >> 4) * 64;
        const int n0g = (blk & 15) * 64;
        const int wave = t >> 6, lane = t & 63;
        const int wm = (wave & 1) * 32, wn = (wave >> 1) * 32;
        const int lm = lane & 15, quad = lane >> 4;
        const int a_r = t >> 2, a_c = (t & 3) * 16;
        const int b_kr = t >> 4, b_l = (t & 15) * 4;
        floatx4 acc[2][2] = {};

        for (int k0 = 0; k0 < 1024; k0 += 64) {
            const float* ap = W1 + (size_t)(m0 + a_r) * 2048 + 1024 + k0 + a_c;
            *(bf16x8*)(MAs + a_r * 72 + a_c) = cvt8(ap);
            *(bf16x8*)(MAs + a_r * 72 + a_c + 8) = cvt8(ap + 8);
#pragma unroll
            for (int ps = 0; ps < 4; ++ps) {
                int kr = b_kr + ps * 16;
                floatx4 v = *(const floatx4*)(Wl + (size_t)(k0 + kr) * 1024 + n0g + b_l);
                MBs[(b_l + 0) * 72 + kr] = (bf16)v.x;
                MBs[(b_l + 1) * 72 + kr] = (bf16)v.y;
                MBs[(b_l + 2) * 72 + kr] = (bf16)v.z;
                MBs[(b_l + 3) * 72 + kr] = (bf16)v.w;
            }
            __syncthreads();
#pragma unroll
            for (int ks = 0; ks < 2; ++ks) {
                bf16x8 af[2], bg[2];
#pragma unroll
                for (int mi = 0; mi < 2; ++mi)
                    af[mi] = *(const bf16x8*)(MAs + (wm + mi * 16 + lm) * 72 + ks * 32 + quad * 8);
#pragma unroll
                for (int ni = 0; ni < 2; ++ni)
                    bg[ni] = *(const bf16x8*)(MBs + (wn + ni * 16 + lm) * 72 + ks * 32 + quad * 8);
#pragma unroll
                for (int mi = 0; mi < 2; ++mi)
#pragma unroll
                    for (int ni = 0; ni < 2; ++ni)
                        acc[mi][ni] = __builtin_amdgcn_mfma_f32_16x16x32_bf16(af[mi], bg[ni], acc[mi][ni], 0, 0, 0);
            }
            __syncthreads();
        }
#pragma unroll
        for (int mi = 0; mi < 2; ++mi)
#pragma unroll
            for (int r = 0; r < 4; ++r)
#pragma unroll
                for (int ni = 0; ni < 2; ++ni)
                    M_bf[(size_t)(m0 + wm + mi * 16 + quad * 4 + r) * 1024 + n0g + wn + ni * 16 + lm] =
                        (bf16)acc[mi][ni][r];
    } else if (blk < PSEG_LAB) {            // label convert
        int i = (blk - PSEG_M) * 256 + t;
        ((bf16x8*)label_b)[i] = cvt8(label + (size_t)i * 8);
    } else if (blk < PSEG_W2) {             // W2 convert
        int i = (blk - PSEG_LAB) * 256 + t;
        ((bf16x8*)W2_b)[i] = cvt8(W2 + (size_t)i * 8);
    } else if (blk < PSEG_PE) {             // Pe, wave per d
        int w = (blk - PSEG_W2) * 4 + (t >> 6);
        int l = t & 63;
        floatx4 wv[5];
#pragma unroll
        for (int k = 0; k < 5; ++k) {
            int g = l + 64 * k;
            wv[k] = (g < 275) ? *(const floatx4*)(Wp + (size_t)w * PDIM + g * 4)
                              : floatx4{0.f, 0.f, 0.f, 0.f};
        }
        for (int b = 0; b < B_SEQ; ++b) {
            float acc = 0.f;
#pragma unroll
            for (int k = 0; k < 5; ++k) {
                int g = l + 64 * k;
                if (g < 275) {
                    floatx4 sv = *(const floatx4*)(seq + (size_t)b * PDIM + g * 4);
                    acc += wv[k].x * sv.x + wv[k].y * sv.y + wv[k].z * sv.z + wv[k].w * sv.w;
                }
            }
#pragma unroll
            for (int off = 32; off; off >>= 1) acc += __shfl_xor(acc, off, 64);
            if (l == 0) Pe[b * DLAT + w] = acc;
        }
    } else {                                // out init
        int i = (blk - PSEG_PE) * 256 + t;
        if (i < NROWS) out[i] = b3[0];
    }
}

// ============ K2: hpb[b,o] = b1[o] + Pe[b,:].W1[o,0:1024]  (f32 exact) ============

__global__ __launch_bounds__(256)
void hpb_kernel(const float* __restrict__ Pe, const float* __restrict__ W1,
                const float* __restrict__ b1, float* __restrict__ hpb) {
    int w = blockIdx.x * 4 + (threadIdx.x >> 6);
    int l = threadIdx.x & 63;
    floatx4 wv[4];
#pragma unroll
    for (int k = 0; k < 4; ++k)
        wv[k] = *(const floatx4*)(W1 + (size_t)w * 2048 + (l + 64 * k) * 4);
    for (int b = 0; b < B_SEQ; ++b) {
        float acc = 0.f;
#pragma unroll
        for (int k = 0; k < 4; ++k) {
            floatx4 pv = *(const floatx4*)(Pe + (size_t)b * DLAT + (l + 64 * k) * 4);
            acc += wv[k].x * pv.x + wv[k].y * pv.y + wv[k].z * pv.z + wv[k].w * pv.w;
        }
#pragma unroll
        for (int off = 32; off; off >>= 1) acc += __shfl_xor(acc, off, 64);
        if (l == 0) hpb[b * DLAT + w] = acc + b1[w];
    }
}

// ============ K3: hl GEMM (label @ M.T) + h1 epilogue — R18 dbuf + R19 layout ====
// 64x128 tile, grid 640 (632 active), R16 XCD-pin decode, R18 dbuf pipeline.
// R19: h1 write goes to K-blocked layout h1[kt][b*5000+n][64] — per (b,kt)
// the block writes 64 rows x 128B = 8KB contiguous.

__global__ __launch_bounds__(256)
void hl_h1_kernel(const bf16* __restrict__ A, const bf16* __restrict__ Bt,
                  const float* __restrict__ hpb, bf16* __restrict__ h1) {
    __shared__ __align__(16) char smem[49152];  // 2 x (As 8KB + Bs 16KB)
    bf16* Ls = (bf16*)smem;                 // 64*136*2 = 17408 B (epilogue)
    float* hpbs = (float*)(smem + 17408);   // 16*128*4 = 8192 B (epilogue)

    const int bid = blockIdx.x;
    const int ylo = bid & 7;
    const int x = (bid >> 3) & 7;
    const int yhi = bid >> 6;
    const int y = ylo + 8 * yhi;            // n-tile 0..79
    if (y >= 79) return;                    // uniform early exit (before syncs)

    const int t = threadIdx.x;
    const int d0 = x * 128;                 // d-tile (8)
    const int n0 = y * 64;                  // n-tile
    const int wave = t >> 6, lane = t & 63;
    const int wm = (wave & 1) * 32;         // n offset within 64
    const int wn = (wave >> 1) * 64;        // d offset within 128
    const int lm = lane & 15, quad = lane >> 4;
    const int sw = lm & 7;
    const int srow = t >> 3;                // 0..31
    const int scg0 = t & 7;
    const int sbase = (t & 192) * 8;

    // stage one K-tile (A 64 rows + B 128 rows) into buffer base
    auto STAGE = [&](int k0, char* base) {
        bf16* As_ = (bf16*)base;
        bf16* Bs_ = (bf16*)(base + 8192);
#pragma unroll
        for (int p = 0; p < 2; ++p) {
            int row = p * 32 + srow;
            int cg = scg0 ^ (row & 7);
            int grow = n0 + row; if (grow >= NLBL) grow = NLBL - 1;
            gload_lds16(A + (size_t)grow * 1024 + k0 + cg * 8, As_ + p * 2048 + sbase);
        }
#pragma unroll
        for (int p = 0; p < 4; ++p) {
            int row = p * 32 + srow;
            int cg = scg0 ^ (row & 7);
            gload_lds16(Bt + (size_t)(d0 + row) * 1024 + k0 + cg * 8, Bs_ + p * 2048 + sbase);
        }
    };

    floatx4 acc[2][4] = {};

    // prologue: tile 0 into buf0
    STAGE(0, smem);
    asm volatile("s_waitcnt vmcnt(0)" ::: "memory");
    barx();

    for (int kt = 0; kt < 16; ++kt) {
        char* cur = smem + (kt & 1) * 24576;
        char* nxt = smem + ((kt + 1) & 1) * 24576;
        const bool pf = (kt < 15);
        if (pf) STAGE((kt + 1) * 64, nxt);  // issue BEFORE compute (R10 rule)

        const bf16* As_ = (const bf16*)cur;
        const bf16* Bs_ = (const bf16*)(cur + 8192);
#pragma unroll
        for (int k = 0; k < 64; k += 32) {
            bf16x8 af[2], bg[4];
            int ko = (((k >> 3) + quad) ^ sw) * 8;
#pragma unroll
            for (int mi = 0; mi < 2; ++mi)
                af[mi] = *(const bf16x8*)(As_ + (wm + mi * 16 + lm) * 64 + ko);
#pragma unroll
            for (int ni = 0; ni < 4; ++ni)
                bg[ni] = *(const bf16x8*)(Bs_ + (wn + ni * 16 + lm) * 64 + ko);
#pragma unroll
            for (int mi = 0; mi < 2; ++mi)
#pragma unroll
                for (int ni = 0; ni < 4; ++ni)
                    acc[mi][ni] = __builtin_amdgcn_mfma_f32_16x16x32_bf16(af[mi], bg[ni], acc[mi][ni], 0, 0, 0);
        }
        if (pf) {
            asm volatile("s_waitcnt vmcnt(0)" ::: "memory");  // next tile landed
            barx();  // all waves done reading cur (reads retired pre-MFMA)
        }
    }

    // epilogue: acc -> Ls (buf0 region; last read of buf0 was kt=14, fenced)
#pragma unroll
    for (int mi = 0; mi < 2; ++mi)
#pragma unroll
        for (int r = 0; r < 4; ++r)
#pragma unroll
            for (int ni = 0; ni < 4; ++ni)
                Ls[(wm + mi * 16 + quad * 4 + r) * 136 + wn + ni * 16 + lm] =
                    (bf16)acc[mi][ni][r];
    {
        int dl = (t & 31) * 4;
        int b = t >> 5;                     // 0..7
        *(floatx4*)(hpbs + b * 128 + dl) =
            *(const floatx4*)(hpb + (size_t)b * DLAT + d0 + dl);
        *(floatx4*)(hpbs + (b + 8) * 128 + dl) =
            *(const floatx4*)(hpb + (size_t)(b + 8) * DLAT + d0 + dl);
    }
    __syncthreads();

    const int g = t & 15;                   // d-granule (16B); g>=8 -> 2nd k-slab
    const int r0 = t >> 4;                  // 0..15 base row
    const size_t slab = (size_t)(2 * x + (g >> 3)) * ((size_t)NROWS * 64);
    const int c8 = (g & 7) * 8;             // col within 64-wide slab row
    bf16x8 hlv[4];
#pragma unroll
    for (int p = 0; p < 4; ++p)
        hlv[p] = *(const bf16x8*)(Ls + (p * 16 + r0) * 136 + g * 8);

    for (int b = 0; b < B_SEQ; ++b) {
        floatx4 h0 = *(const floatx4*)(hpbs + b * 128 + g * 8);
        floatx4 h4 = *(const floatx4*)(hpbs + b * 128 + g * 8 + 4);
#pragma unroll
        for (int p = 0; p < 4; ++p) {
            int n = n0 + p * 16 + r0;
            if (n >= NLBL) continue;
            bf16x8 o;
            o[0] = (bf16)fmaxf((float)hlv[p][0] + h0.x, 0.f);
            o[1] = (bf16)fmaxf((float)hlv[p][1] + h0.y, 0.f);
            o[2] = (bf16)fmaxf((float)hlv[p][2] + h0.z, 0.f);
            o[3] = (bf16)fmaxf((float)hlv[p][3] + h0.w, 0.f);
            o[4] = (bf16)fmaxf((float)hlv[p][4] + h4.x, 0.f);
            o[5] = (bf16)fmaxf((float)hlv[p][5] + h4.y, 0.f);
            o[6] = (bf16)fmaxf((float)hlv[p][6] + h4.z, 0.f);
            o[7] = (bf16)fmaxf((float)hlv[p][7] + h4.w, 0.f);
            *(bf16x8*)(h1 + slab + ((size_t)b * NLBL + n) * 64 + c8) = o;
        }
    }
}

// ============ K4: main GEMM h1 @ W2.T — R14 schedule (frozen) + R19 A-layout ====
// 512 thr = 8 waves (2M x 4N), BK=64, 2-dbuf, stage A in ph1 / B in ph2,
// single vmcnt(0) at end of ph4, ks-outer MFMA. A reads from K-blocked
// h1[kt][row][64]: 32KB contiguous per K-tile (was 256 x 128B @ 2KB stride).

__device__ __forceinline__ void stage_A256(const bf16* __restrict__ src, bf16* dst,
                                           int m0, int kc, int t) {
    const bf16* slab = src + (size_t)(kc >> 6) * ((size_t)NROWS * 64);
#pragma unroll
    for (int i = 0; i < 4; ++i) {
        int s = t + i * 512;                // 0..2047
        int row = s >> 3;                   // 0..255
        int cg = (s & 7) ^ (row & 7);
        int grow = m0 + row;
        if (grow >= NROWS) grow = NROWS - 1;    // last m-tile is half-valid
        gload_lds16(slab + (size_t)grow * 64 + cg * 8, dst + s * 8);
    }
}

__device__ __forceinline__ void stage_B256(const bf16* __restrict__ src, bf16* dst,
                                           int n0, int kc, int t) {
#pragma unroll
    for (int i = 0; i < 4; ++i) {
        int s = t + i * 512;
        int row = s >> 3;
        int cg = (s & 7) ^ (row & 7);
        gload_lds16(src + (size_t)(n0 + row) * 1024 + kc + cg * 8, dst + s * 8);
    }
}

__global__ __launch_bounds__(512, 2)
void gemm_h2(const bf16* __restrict__ h1, const bf16* __restrict__ W2b,
             const float* __restrict__ b2, const float* __restrict__ W3,
             float* __restrict__ out) {
    __shared__ bf16 As[32768];              // 2 x [256][64]
    __shared__ bf16 Bs[32768];              // 2 x [256][64]
    const int t = threadIdx.x;

    // bijective XCD swizzle over nwg=1252 (q=156, r=4; m204 formula)
    int orig = blockIdx.x;
    int xcd = orig & 7, idx = orig >> 3;
    int wg = (xcd < 4 ? xcd * 157 : 628 + (xcd - 4) * 156) + idx;
    const int mt = wg >> 2, nt = wg & 3;    // 313 m-tiles x 4 n-tiles
    const int m0 = mt * 256, n0 = nt * 256;

    const int wave = t >> 6, lane = t & 63;
    const int wr = wave >> 2, wc = wave & 3;
    const int wrow = wr * 128, wcol = wc * 64;
    const int lm = lane & 15, quad = lane >> 4;
    const int swz = lm & 7;

    floatx4 acc[8][4] = {};

    // prologue: stage K-tile 0 into dbuf 0
    stage_A256(h1, As, m0, 0, t);
    stage_B256(W2b, Bs, n0, 0, t);
    asm volatile("s_waitcnt vmcnt(0)" ::: "memory");
    barx();

    for (int kt = 0; kt < 16; ++kt) {
        const int db = kt & 1;
        const bf16* Ad = As + db * 16384;
        const bf16* Bd = Bs + db * 16384;
        bf16* An = As + (db ^ 1) * 16384;
        bf16* Bn = Bs + (db ^ 1) * 16384;
        const bool pf = (kt < 15);
        const int kc = (kt + 1) * 64;

        bf16x8 a[4][2], blo[2][2], bhi[2][2];

        // ---- phase 1: frags A(mh0)+B(nh0) [12 ds_read_b128]; stage next A ----
#pragma unroll
        for (int mi = 0; mi < 4; ++mi) {
            const bf16* rp = Ad + (wrow + mi * 16 + lm) * 64;
            a[mi][0] = *(const bf16x8*)(rp + ((quad ^ swz) << 3));
            a[mi][1] = *(const bf16x8*)(rp + (((4 + quad) ^ swz) << 3));
        }
#pragma unroll
        for (int ni = 0; ni < 2; ++ni) {
            const bf16* rp = Bd + (wcol + ni * 16 + lm) * 64;
            blo[ni][0] = *(const bf16x8*)(rp + ((quad ^ swz) << 3));
            blo[ni][1] = *(const bf16x8*)(rp + (((4 + quad) ^ swz) << 3));
        }
        if (pf) stage_A256(h1, An, m0, kc, t);
        barx();
        __builtin_amdgcn_s_setprio(1);
#pragma unroll
        for (int ks = 0; ks < 2; ++ks)
#pragma unroll
            for (int mi = 0; mi < 4; ++mi)
#pragma unroll
                for (int ni = 0; ni < 2; ++ni)
                    acc[mi][ni] = __builtin_amdgcn_mfma_f32_16x16x32_bf16(a[mi][ks], blo[ni][ks], acc[mi][ni], 0, 0, 0);
        __builtin_amdgcn_s_setprio(0);
        barx();

        // ---- phase 2: frags B(nh1) [4 ds_read_b128]; stage next B ----
#pragma unroll
        for (int ni = 0; ni < 2; ++ni) {
            const bf16* rp = Bd + (wcol + 32 + ni * 16 + lm) * 64;
            bhi[ni][0] = *(const bf16x8*)(rp + ((quad ^ swz) << 3));
            bhi[ni][1] = *(const bf16x8*)(rp + (((4 + quad) ^ swz) << 3));
        }
        if (pf) stage_B256(W2b, Bn, n0, kc, t);
        barx();
        __builtin_amdgcn_s_setprio(1);
#pragma unroll
        for (int ks = 0; ks < 2; ++ks)
#pragma unroll
            for (int mi = 0; mi < 4; ++mi)
#pragma unroll
                for (int ni = 0; ni < 2; ++ni)
                    acc[mi][2 + ni] = __builtin_amdgcn_mfma_f32_16x16x32_bf16(a[mi][ks], bhi[ni][ks], acc[mi][2 + ni], 0, 0, 0);
        __builtin_amdgcn_s_setprio(0);
        barx();

        // ---- phase 3: frags A(mh1) [8 ds_read_b128] ----
#pragma unroll
        for (int mi = 0; mi < 4; ++mi) {
            const bf16* rp = Ad + (wrow + 64 + mi * 16 + lm) * 64;
            a[mi][0] = *(const bf16x8*)(rp + ((quad ^ swz) << 3));
            a[mi][1] = *(const bf16x8*)(rp + (((4 + quad) ^ swz) << 3));
        }
        barx();
        __builtin_amdgcn_s_setprio(1);
#pragma unroll
        for (int ks = 0; ks < 2; ++ks)
#pragma unroll
            for (int mi = 0; mi < 4; ++mi)
#pragma unroll
                for (int ni = 0; ni < 2; ++ni)
                    acc[4 + mi][2 + ni] = __builtin_amdgcn_mfma_f32_16x16x32_bf16(a[mi][ks], bhi[ni][ks], acc[4 + mi][2 + ni], 0, 0, 0);
        __builtin_amdgcn_s_setprio(0);
        barx();

        // ---- phase 4: pure-reg MFMA; drain staging loads; buffer swap ----
        __builtin_amdgcn_s_setprio(1);
#pragma unroll
        for (int ks = 0; ks < 2; ++ks)
#pragma unroll
            for (int mi = 0; mi < 4; ++mi)
#pragma unroll
                for (int ni = 0; ni < 2; ++ni)
                    acc[4 + mi][ni] = __builtin_amdgcn_mfma_f32_16x16x32_bf16(a[mi][ks], blo[ni][ks], acc[4 + mi][ni], 0, 0, 0);
        __builtin_amdgcn_s_setprio(0);
        asm volatile("s_waitcnt vmcnt(0)" ::: "memory");
        barx();
    }

    // fused epilogue: out[row] += sum_col relu(acc + b2) * W3
    float w3v[4], b2v[4];
#pragma unroll
    for (int ni = 0; ni < 4; ++ni) {
        int col = n0 + wcol + ni * 16 + lm;
        w3v[ni] = W3[col];
        b2v[ni] = b2[col];
    }
#pragma unroll
    for (int mi = 0; mi < 8; ++mi) {
#pragma unroll
        for (int r = 0; r < 4; ++r) {
            float sacc = 0.f;
#pragma unroll
            for (int ni = 0; ni < 4; ++ni)
                sacc += fmaxf(acc[mi][ni][r] + b2v[ni], 0.f) * w3v[ni];
            sacc += __shfl_xor(sacc, 1, 64);
            sacc += __shfl_xor(sacc, 2, 64);
            sacc += __shfl_xor(sacc, 4, 64);
            sacc += __shfl_xor(sacc, 8, 64);
            int row = m0 + wrow + mi * 16 + quad * 4 + r;
            if (lm == 0 && row < NROWS)
                atomicAdd(out + row, sacc);
        }
    }
}

// ---------------- launch ----------------

extern "C" void kernel_launch(void* const* d_in, const int* in_sizes, int n_in,
                              void* d_out, int out_size, void* d_ws, size_t ws_size,
                              hipStream_t stream) {
    const float* seq   = (const float*)d_in[0];
    const float* label = (const float*)d_in[1];
    const float* Wp    = (const float*)d_in[2];
    const float* Wl    = (const float*)d_in[3];
    const float* W1    = (const float*)d_in[4];
    const float* b1    = (const float*)d_in[5];
    const float* W2    = (const float*)d_in[6];
    const float* b2    = (const float*)d_in[7];
    const float* W3    = (const float*)d_in[8];
    const float* b3    = (const float*)d_in[9];
    float* out = (float*)d_out;
    (void)n_in; (void)in_sizes; (void)out_size; (void)ws_size;

    size_t off = 0;
    auto alloc = [&](size_t bytes) {
        void* p = (char*)d_ws + off;
        off += (bytes + 255) & ~(size_t)255;
        return p;
    };
    bf16* label_b = (bf16*)alloc((size_t)NLBL * 1024 * 2);
    bf16* W2_b    = (bf16*)alloc((size_t)1024 * 1024 * 2);
    bf16* M_bf    = (bf16*)alloc((size_t)1024 * 1024 * 2);
    float* Pe     = (float*)alloc((size_t)B_SEQ * 1024 * 4);
    float* hpb    = (float*)alloc((size_t)B_SEQ * 1024 * 4);
    bf16* h1      = (bf16*)alloc((size_t)NROWS * 1024 * 2);   // K-blocked [16][80000][64]

    prep_kernel<<<PSEG_END, 256, 0, stream>>>(label, label_b, W2, W2_b, W1, Wl,
                                              M_bf, seq, Wp, Pe, out, b3);
    hpb_kernel<<<256, 256, 0, stream>>>(Pe, W1, b1, hpb);
    hl_h1_kernel<<<640, 256, 0, stream>>>(label_b, M_bf, hpb, h1);
    gemm_h2<<<1252, 512, 0, stream>>>(h1, W2_b, b2, W3, out);
}